// Round 12
// baseline (244.408 us; speedup 1.0000x reference)
//
#include <hip/hip_runtime.h>
#include <hip/hip_bf16.h>
#include <hip/hip_fp16.h>
#include <cstdint>

#define N_NODES 100000
#define N_EDGES 1600000
#define FDIM 64
#define NPAIRS 200000
#define NB 391          // dst buckets: ceil(100000/256)
#define BCAP 4864       // bucket fill capacity (avg 4092, +12 sigma)
#define SSTR 5632       // bucket region stride (>= BCAP + 256*3 row padding)
#define EPB 6250        // edges per block in p1 passes (256 blocks)

typedef __attribute__((ext_vector_type(8))) short short8;
typedef __attribute__((ext_vector_type(8))) _Float16 half8;
typedef __attribute__((ext_vector_type(4))) float floatx4;

__device__ __forceinline__ unsigned short bf16_rtne(float f) {
    unsigned u = __float_as_uint(f);
    unsigned r = (u + 0x7fffu + ((u >> 16) & 1u)) >> 16;
    return (unsigned short)r;
}

__device__ __forceinline__ void split8_rtne(const float* f, short8& hi, short8& lo) {
#pragma unroll
    for (int j = 0; j < 8; ++j) {
        unsigned short h = bf16_rtne(f[j]);
        hi[j] = (short)h;
        float hf = __uint_as_float(((unsigned)h) << 16);
        lo[j] = (short)bf16_rtne(f[j] - hf);
    }
}

__device__ __forceinline__ void split8_trunc(const float* f, short8& hi, short8& lo) {
#pragma unroll
    for (int j = 0; j < 8; ++j) {
        unsigned u = __float_as_uint(f[j]);
        hi[j] = (short)(unsigned short)(u >> 16);
        float hf = __uint_as_float(u & 0xffff0000u);
        float r = f[j] - hf;
        lo[j] = (short)(unsigned short)(__float_as_uint(r) >> 16);
    }
}

// K0: h0 = 2*x (overflow-path accumulator) AND xh = fp16(x); zero ovfFlag.
__global__ void k0_init(const float4* __restrict__ x4, float4* __restrict__ h04,
                        __half* __restrict__ xh, int* __restrict__ ovfFlag) {
    int i = blockIdx.x * blockDim.x + threadIdx.x;
    if (i == 0) ovfFlag[0] = 0;
    if (i < N_NODES * FDIM / 4) {
        float4 v = x4[i];
        float4 d = {2.f * v.x, 2.f * v.y, 2.f * v.z, 2.f * v.w};
        h04[i] = d;
        ushort4 o;
        o.x = __half_as_ushort(__float2half(v.x));
        o.y = __half_as_ushort(__float2half(v.y));
        o.z = __half_as_ushort(__float2half(v.z));
        o.w = __half_as_ushort(__float2half(v.w));
        ((ushort4*)xh)[i] = o;
    }
}

// P1a: per-block LDS histogram of dst buckets -> matrix[block][bucket]
__global__ void __launch_bounds__(256) p1a_hist(const int* __restrict__ dst,
                                                int* __restrict__ matrix) {
    __shared__ int hist[NB];
    int tid = threadIdx.x, blk = blockIdx.x;
    for (int i = tid; i < NB; i += 256) hist[i] = 0;
    __syncthreads();
    int base = blk * EPB;
    for (int i = tid; i < EPB; i += 256) {
        int d = dst[base + i];
        atomicAdd(&hist[d >> 8], 1);
    }
    __syncthreads();
    for (int i = tid; i < NB; i += 256) matrix[blk * NB + i] = hist[i];
}

// P1b: per-bucket exclusive scan over 256 block counts (in-place) + totals.
__global__ void __launch_bounds__(256) p1b_scan(int* __restrict__ matrix,
                                                int* __restrict__ bucketCnt) {
    __shared__ int s[256];
    int b = blockIdx.x, t = threadIdx.x;
    int v = matrix[t * NB + b];
    s[t] = v;
    __syncthreads();
    for (int off = 1; off < 256; off <<= 1) {
        int u = (t >= off) ? s[t - off] : 0;
        __syncthreads();
        s[t] += u;
        __syncthreads();
    }
    matrix[t * NB + b] = s[t] - v;           // exclusive prefix
    if (t == 255) bucketCnt[b] = s[255];
}

// P1c: scatter packed (dlow<<17 | src) into bucket regions (stride SSTR).
// Overflow beyond BCAP: correct h0 atomics + set ovfFlag (k2 then reads h0).
__global__ void __launch_bounds__(256) p1c_scatter(const int* __restrict__ src,
        const int* __restrict__ dst, const float* __restrict__ x,
        float* __restrict__ h0, const int* __restrict__ matrix,
        int* __restrict__ bucketArr, int* __restrict__ ovfFlag) {
    __shared__ int cur[NB];
    int tid = threadIdx.x, blk = blockIdx.x;
    for (int i = tid; i < NB; i += 256) cur[i] = matrix[blk * NB + i];
    __syncthreads();
    int base = blk * EPB;
    for (int i = tid; i < EPB; i += 256) {
        int e = base + i;
        int s = src[e], d = dst[e];
        int b = d >> 8;
        int pos = atomicAdd(&cur[b], 1);
        if (pos < BCAP) {
            bucketArr[(size_t)b * SSTR + pos] = ((d & 255) << 17) | s;
        } else {
            atomicOr(ovfFlag, 1);
            const float* xr = x + (size_t)s * FDIM;
            float* hr = h0 + (size_t)d * FDIM;
            for (int f = 0; f < FDIM; ++f) atomicAdd(&hr[f], xr[f]);
        }
    }
}

// P2: per-bucket fine counting sort IN-PLACE (stage bucket into LDS, scatter
// src ids back to the same global region at sorted+padded positions).
__global__ void __launch_bounds__(256) p2_build(int* __restrict__ bucketArr,
        const int* __restrict__ bucketCnt, int* __restrict__ rowptr,
        int* __restrict__ deg) {
    __shared__ int ebuf[BCAP];               // 19.5 KB
    __shared__ int hist[256], sc[256], cur[256];
    int b = blockIdx.x, t = threadIdx.x;
    int cnt = bucketCnt[b];
    if (cnt > BCAP) cnt = BCAP;
    int* arr = bucketArr + (size_t)b * SSTR;
    hist[t] = 0;
    __syncthreads();
    for (int i = t; i < cnt; i += 256) {
        int e = arr[i];
        ebuf[i] = e;
        atomicAdd(&hist[(e >> 17) & 255], 1);
    }
    __syncthreads();
    int h = hist[t];
    int pc = (h + 3) & ~3;                   // pad row to 4 ints
    sc[t] = pc;
    __syncthreads();
    for (int off = 1; off < 256; off <<= 1) {
        int u = (t >= off) ? sc[t - off] : 0;
        __syncthreads();
        sc[t] += u;
        __syncthreads();
    }
    int rbase = sc[t] - pc;                  // exclusive padded prefix
    cur[t] = rbase;
    int n = (b << 8) + t;
    if (n < N_NODES) {
        rowptr[n] = b * SSTR + rbase;
        deg[n] = h;
    }
    __syncthreads();
    for (int i = t; i < cnt; i += 256) {
        int e = ebuf[i];
        int dl = (e >> 17) & 255;
        int pos = atomicAdd(&cur[dl], 1);
        arr[pos] = e & 0x1FFFF;
    }
}

// K2: TWO independent node streams per thread (R12 change): thread handles
// (node pair, chunk) -> ~40 outstanding lines/thread vs ~20; 800K threads.
// R11 evidence: line rate scales with MLP (R7 97G lines/s vs R11 72G).
__device__ __forceinline__ void addrow(float4& acc, const __half* __restrict__ xh,
                                       int s, int fq) {
    float2 raw = *(const float2*)(xh + (size_t)s * 64 + fq * 4);
    __half2 a = *(__half2*)&raw.x;
    __half2 b = *(__half2*)&raw.y;
    float2 fa = __half22float2(a);
    float2 fb = __half22float2(b);
    acc.x += fa.x; acc.y += fa.y; acc.z += fb.x; acc.w += fb.y;
}

__device__ __forceinline__ float4 selfterm(const __half* __restrict__ xh,
                                           int n, int fq) {
    float2 raw = *(const float2*)(xh + (size_t)n * 64 + fq * 4);
    __half2 a = *(__half2*)&raw.x;
    __half2 b = *(__half2*)&raw.y;
    float2 fa = __half22float2(a);
    float2 fb = __half22float2(b);
    return (float4){2.f * fa.x, 2.f * fa.y, 2.f * fb.x, 2.f * fb.y};
}

__global__ void __launch_bounds__(256) k2_agg(const __half* __restrict__ xh,
                       float4* __restrict__ h04, const int* __restrict__ deg,
                       const int* __restrict__ rowptr, const int* __restrict__ csr,
                       const int* __restrict__ ovfFlag) {
    int gid = blockIdx.x * 256 + threadIdx.x;   // 800K = (N/2)*16
    int n0 = (gid >> 4) * 2, n1 = n0 + 1, fq = gid & 15;
    int dc0 = deg[n0], dc1 = deg[n1];
    const int4* srow0 = (const int4*)(csr + rowptr[n0]);
    const int4* srow1 = (const int4*)(csr + rowptr[n1]);
    float4 acc0, acc1;
    if (ovfFlag[0]) {
        acc0 = h04[(size_t)n0 * 16 + fq];
        acc1 = h04[(size_t)n1 * 16 + fq];
    } else {
        acc0 = selfterm(xh, n0, fq);
        acc1 = selfterm(xh, n1, fq);
    }
    int dcm = dc0 > dc1 ? dc0 : dc1;
    for (int i = 0; i < dcm; i += 8) {
        int4 a4, a5, b4, b5;
        if (i < dc0)     a4 = srow0[i >> 2];
        if (i + 4 < dc0) a5 = srow0[(i >> 2) + 1];
        if (i < dc1)     b4 = srow1[i >> 2];
        if (i + 4 < dc1) b5 = srow1[(i >> 2) + 1];
        if (i < dc0)     addrow(acc0, xh, a4.x, fq);
        if (i < dc1)     addrow(acc1, xh, b4.x, fq);
        if (i + 1 < dc0) addrow(acc0, xh, a4.y, fq);
        if (i + 1 < dc1) addrow(acc1, xh, b4.y, fq);
        if (i + 2 < dc0) addrow(acc0, xh, a4.z, fq);
        if (i + 2 < dc1) addrow(acc1, xh, b4.z, fq);
        if (i + 3 < dc0) addrow(acc0, xh, a4.w, fq);
        if (i + 3 < dc1) addrow(acc1, xh, b4.w, fq);
        if (i + 4 < dc0) addrow(acc0, xh, a5.x, fq);
        if (i + 4 < dc1) addrow(acc1, xh, b5.x, fq);
        if (i + 5 < dc0) addrow(acc0, xh, a5.y, fq);
        if (i + 5 < dc1) addrow(acc1, xh, b5.y, fq);
        if (i + 6 < dc0) addrow(acc0, xh, a5.z, fq);
        if (i + 6 < dc1) addrow(acc1, xh, b5.z, fq);
        if (i + 7 < dc0) addrow(acc0, xh, a5.w, fq);
        if (i + 7 < dc1) addrow(acc1, xh, b5.w, fq);
    }
    h04[(size_t)n0 * 16 + fq] = acc0;
    h04[(size_t)n1 * 16 + fq] = acc1;
}

// K3: node MLP via split-bf16 MFMA (16 nodes/wave); fp16 output hh.
__global__ void __launch_bounds__(256) k3_mfma(const float* __restrict__ h,
        __half* __restrict__ hh,
        const float* __restrict__ w1, const float* __restrict__ b1,
        const float* __restrict__ w2, const float* __restrict__ b2) {
    __shared__ short8 W1H[512], W1L[512], W2H[512], W2L[512];  // 32 KB
    __shared__ float Tbuf[4 * 16 * 68];                        // 17.4 KB
    int tid = threadIdx.x;
    for (int f = tid; f < 512; f += 256) {
        int flane = f & 63, st = f >> 6;
        int t = st & 3, s = st >> 2;
        int fq = flane >> 4, fp = flane & 15;
        int n = t * 16 + fp;
        int K0 = s * 32 + fq * 8;
        float wv[8];
#pragma unroll
        for (int j = 0; j < 8; ++j) wv[j] = w1[(K0 + j) * 64 + n];
        short8 hi, lo;
        split8_rtne(wv, hi, lo);
        W1H[f] = hi; W1L[f] = lo;
#pragma unroll
        for (int j = 0; j < 8; ++j) wv[j] = w2[(K0 + j) * 64 + n];
        split8_rtne(wv, hi, lo);
        W2H[f] = hi; W2L[f] = lo;
    }
    __syncthreads();
    int lane = tid & 63;
    int q = lane >> 4, p = lane & 15;
    int wtid0 = blockIdx.x * 4 + (tid >> 6);
    int wtid = wtid0 < 6249 ? wtid0 : 6249;
    int n0 = wtid * 16;
    float b1t[4], b2t[4];
#pragma unroll
    for (int t = 0; t < 4; ++t) {
        b1t[t] = b1[t * 16 + p];
        b2t[t] = b2[t * 16 + p];
    }
    const float* hrow = h + (size_t)(n0 + p) * 64;
    float4 a0 = *(const float4*)(hrow + q * 8);
    float4 a1 = *(const float4*)(hrow + q * 8 + 4);
    float4 a2 = *(const float4*)(hrow + 32 + q * 8);
    float4 a3 = *(const float4*)(hrow + 32 + q * 8 + 4);
    float f0[8] = {a0.x, a0.y, a0.z, a0.w, a1.x, a1.y, a1.z, a1.w};
    float f1[8] = {a2.x, a2.y, a2.z, a2.w, a3.x, a3.y, a3.z, a3.w};
    short8 Ah0, Al0, Ah1, Al1;
    split8_trunc(f0, Ah0, Al0);
    split8_trunc(f1, Ah1, Al1);
    floatx4 acc[4];
#pragma unroll
    for (int t = 0; t < 4; ++t) acc[t] = (floatx4){0.f, 0.f, 0.f, 0.f};
#pragma unroll
    for (int t = 0; t < 4; ++t) {
        short8 bh = W1H[t * 64 + lane], bl = W1L[t * 64 + lane];
        acc[t] = __builtin_amdgcn_mfma_f32_16x16x32_bf16(Ah0, bh, acc[t], 0, 0, 0);
        acc[t] = __builtin_amdgcn_mfma_f32_16x16x32_bf16(Al0, bh, acc[t], 0, 0, 0);
        acc[t] = __builtin_amdgcn_mfma_f32_16x16x32_bf16(Ah0, bl, acc[t], 0, 0, 0);
        bh = W1H[(4 + t) * 64 + lane]; bl = W1L[(4 + t) * 64 + lane];
        acc[t] = __builtin_amdgcn_mfma_f32_16x16x32_bf16(Ah1, bh, acc[t], 0, 0, 0);
        acc[t] = __builtin_amdgcn_mfma_f32_16x16x32_bf16(Al1, bh, acc[t], 0, 0, 0);
        acc[t] = __builtin_amdgcn_mfma_f32_16x16x32_bf16(Ah1, bl, acc[t], 0, 0, 0);
    }
    float* T = Tbuf + (tid >> 6) * (16 * 68);
#pragma unroll
    for (int t = 0; t < 4; ++t) {
#pragma unroll
        for (int r = 0; r < 4; ++r)
            T[(q * 4 + r) * 68 + t * 16 + p] = fmaxf(acc[t][r] + b1t[t], 0.f);
    }
    const float* Tp = T + p * 68;
    float4 u0 = *(const float4*)(Tp + q * 8);
    float4 u1 = *(const float4*)(Tp + q * 8 + 4);
    float4 u2 = *(const float4*)(Tp + 32 + q * 8);
    float4 u3 = *(const float4*)(Tp + 32 + q * 8 + 4);
    float g0[8] = {u0.x, u0.y, u0.z, u0.w, u1.x, u1.y, u1.z, u1.w};
    float g1[8] = {u2.x, u2.y, u2.z, u2.w, u3.x, u3.y, u3.z, u3.w};
    split8_trunc(g0, Ah0, Al0);
    split8_trunc(g1, Ah1, Al1);
#pragma unroll
    for (int t = 0; t < 4; ++t) acc[t] = (floatx4){0.f, 0.f, 0.f, 0.f};
#pragma unroll
    for (int t = 0; t < 4; ++t) {
        short8 bh = W2H[t * 64 + lane], bl = W2L[t * 64 + lane];
        acc[t] = __builtin_amdgcn_mfma_f32_16x16x32_bf16(Ah0, bh, acc[t], 0, 0, 0);
        acc[t] = __builtin_amdgcn_mfma_f32_16x16x32_bf16(Al0, bh, acc[t], 0, 0, 0);
        acc[t] = __builtin_amdgcn_mfma_f32_16x16x32_bf16(Ah0, bl, acc[t], 0, 0, 0);
        bh = W2H[(4 + t) * 64 + lane]; bl = W2L[(4 + t) * 64 + lane];
        acc[t] = __builtin_amdgcn_mfma_f32_16x16x32_bf16(Ah1, bh, acc[t], 0, 0, 0);
        acc[t] = __builtin_amdgcn_mfma_f32_16x16x32_bf16(Al1, bh, acc[t], 0, 0, 0);
        acc[t] = __builtin_amdgcn_mfma_f32_16x16x32_bf16(Ah1, bl, acc[t], 0, 0, 0);
    }
    if (wtid0 < 6250) {
#pragma unroll
        for (int t = 0; t < 4; ++t) {
#pragma unroll
            for (int r = 0; r < 4; ++r)
                hh[(size_t)(n0 + q * 4 + r) * 64 + t * 16 + p] =
                    __float2half(fmaxf(acc[t][r] + b2t[t], 0.f));
        }
    }
}

// K4: pair decoder via plain fp16 MFMA (f32 accum), 16 pairs/wave-task.
__global__ void __launch_bounds__(256) k4_pair(const __half* __restrict__ hh,
                        const int* __restrict__ qidx,
                        const float* __restrict__ dw1, const float* __restrict__ db1,
                        const float* __restrict__ dw2, const float* __restrict__ db2,
                        float* __restrict__ out, int numWaves) {
    __shared__ half8 BF[2048];   // [s(8)][t(4)][lane(64)] -> 32 KB
    int tid = threadIdx.x;
    for (int f = tid; f < 2048; f += 256) {
        int lane = f & 63, st = f >> 6;
        int t = st & 3, s = st >> 2;
        int q = lane >> 4, nl = lane & 15;
        int n = t * 16 + nl;
        int K0 = s * 32 + q * 8;
        half8 hv;
#pragma unroll
        for (int j = 0; j < 8; ++j) hv[j] = (_Float16)dw1[(K0 + j) * 64 + n];
        BF[f] = hv;
    }
    __syncthreads();
    int lane = tid & 63;
    int q = lane >> 4, nl = lane & 15;
    float db1t[4], dw2t[4];
#pragma unroll
    for (int t = 0; t < 4; ++t) {
        db1t[t] = db1[t * 16 + nl];
        dw2t[t] = dw2[t * 16 + nl];
    }
    float db2v = db2[0];
    int wid = (blockIdx.x * 256 + tid) >> 6;
    for (int task = wid; task < NPAIRS / 16; task += numWaves) {
        int p0 = task * 16;
        int i1 = qidx[p0 + nl];
        int i2 = qidx[NPAIRS + p0 + nl];
        const half8* r1 = (const half8*)(hh + (size_t)i1 * 64);
        const half8* r2 = (const half8*)(hh + (size_t)i2 * 64);
        half8 e1a = r1[q],     e1b = r1[4 + q];
        half8 e2a = r2[q],     e2b = r2[4 + q];
        half8 sA = e1a + e2a,  sB = e1b + e2b;    // v_pk_add_f16
        half8 pA = e1a * e2a,  pB = e1b * e2b;    // v_pk_mul_f16
        floatx4 acc[4];
#pragma unroll
        for (int t = 0; t < 4; ++t) acc[t] = (floatx4){0.f, 0.f, 0.f, 0.f};

#define DO_STEP(S, AV)                                                        \
        _Pragma("unroll")                                                     \
        for (int t = 0; t < 4; ++t)                                           \
            acc[t] = __builtin_amdgcn_mfma_f32_16x16x32_f16(                  \
                (AV), BF[((S) * 4 + t) * 64 + lane], acc[t], 0, 0, 0);

        DO_STEP(0, sA)   // section 0 (e1+e2), k 0..31
        DO_STEP(1, sB)   // section 0, k 32..63
        DO_STEP(2, pA)   // section 1 (e1*e2)
        DO_STEP(3, pB)
        DO_STEP(4, e1a)  // section 2 (e1)
        DO_STEP(5, e1b)
        DO_STEP(6, e2a)  // section 3 (e2)
        DO_STEP(7, e2b)
#undef DO_STEP

        float part[4] = {0.f, 0.f, 0.f, 0.f};
#pragma unroll
        for (int t = 0; t < 4; ++t) {
#pragma unroll
            for (int r = 0; r < 4; ++r)
                part[r] = fmaf(fmaxf(acc[t][r] + db1t[t], 0.f), dw2t[t], part[r]);
        }
#pragma unroll
        for (int off = 1; off < 16; off <<= 1) {
#pragma unroll
            for (int r = 0; r < 4; ++r) part[r] += __shfl_xor(part[r], off, 64);
        }
        if (nl == 0) {
#pragma unroll
            for (int r = 0; r < 4; ++r) out[p0 + q * 4 + r] = part[r] + db2v;
        }
    }
}

extern "C" void kernel_launch(void* const* d_in, const int* in_sizes, int n_in,
                              void* d_out, int out_size, void* d_ws, size_t ws_size,
                              hipStream_t stream) {
    const float* x    = (const float*)d_in[0];   // [N,64]
    const int*   eidx = (const int*)d_in[1];     // [2,E]
    const int*   qidx = (const int*)d_in[3];     // [2,P]
    const float* w1   = (const float*)d_in[4];
    const float* b1   = (const float*)d_in[5];
    const float* w2   = (const float*)d_in[6];
    const float* b2   = (const float*)d_in[7];
    const float* dw1  = (const float*)d_in[8];   // [256,64]
    const float* db1  = (const float*)d_in[9];
    const float* dw2  = (const float*)d_in[10];  // [64]
    const float* db2  = (const float*)d_in[11];  // [1]
    float* out = (float*)d_out;                  // [P]

    // ws layout (48.41 MB total, < 51.2 MB proven-safe; 16B aligned):
    //   h0        @ 0          : 25,600,000 B  (f32 overflow accumulator /
    //                                           k2 out / k3 in)
    //   xh / hh   @ 25,600,000 : 12,800,000 B  (fp16 x for k2; reused as
    //                                           fp16 h for k3->k4)
    //   bucketArr @ 38,400,000 :  8,808,448 B  (391 x 5632 x 4, in-place CSR)
    //   rowptr    @ 47,208,448 :    400,000 B
    //   deg       @ 47,608,448 :    400,000 B
    //   matrix    @ 48,008,448 :    400,384 B
    //   bucketCnt @ 48,408,832 :      1,564 B
    //   ovfFlag   @ 48,410,396 :          4 B
    char* ws = (char*)d_ws;
    float*  h0        = (float*)ws;
    __half* xh        = (__half*)(ws + 25600000);
    int*    bucketArr = (int*)(ws + 38400000);
    int*    rowptr    = (int*)(ws + 47208448);
    int*    deg       = (int*)(ws + 47608448);
    int*    matrix    = (int*)(ws + 48008448);
    int*    bucketCnt = (int*)(ws + 48408832);
    int*    ovfFlag   = (int*)(ws + 48410396);

    const int* src = eidx;
    const int* dst = eidx + N_EDGES;

    k0_init<<<6250, 256, 0, stream>>>((const float4*)x, (float4*)h0, xh, ovfFlag);
    p1a_hist<<<256, 256, 0, stream>>>(dst, matrix);
    p1b_scan<<<NB, 256, 0, stream>>>(matrix, bucketCnt);
    p1c_scatter<<<256, 256, 0, stream>>>(src, dst, x, h0, matrix, bucketArr,
                                         ovfFlag);
    p2_build<<<NB, 256, 0, stream>>>(bucketArr, bucketCnt, rowptr, deg);
    // K2: 2 nodes/thread -> 800K threads = 3125 x 256
    k2_agg<<<3125, 256, 0, stream>>>(xh, (float4*)h0, deg, rowptr, bucketArr,
                                     ovfFlag);
    k3_mfma<<<1563, 256, 0, stream>>>(h0, xh, w1, b1, w2, b2);
    const int blocks4 = 625;
    k4_pair<<<blocks4, 256, 0, stream>>>(xh, qidx, dw1, db1, dw2, db2, out,
                                         blocks4 * 4);
}

// Round 13
// 215.643 us; speedup vs baseline: 1.1334x; 1.1334x over previous
//
#include <hip/hip_runtime.h>
#include <hip/hip_bf16.h>
#include <hip/hip_fp16.h>
#include <cstdint>

#define N_NODES 100000
#define N_EDGES 1600000
#define FDIM 64
#define NPAIRS 200000
#define NB 391          // dst buckets: ceil(100000/256)
#define BCAP 4864       // bucket fill capacity (avg 4092, +12 sigma)
#define SSTR 5632       // bucket region stride (>= BCAP + 256*3 row padding)
#define EPB 6250        // edges per hist/scatter block (256 blocks)

typedef __attribute__((ext_vector_type(8))) _Float16 half8;
typedef __attribute__((ext_vector_type(4))) float floatx4;

// K0 (fused with old p1a): xh = fp16(x) for all 6250 blocks; blocks < 256
// also LDS-histogram dst -> matrix[block][bucket]. No h0 init anymore
// (overflow now goes through ovfList, not f32 atomics).
__global__ void __launch_bounds__(256) k0_fused(const float4* __restrict__ x4,
        __half* __restrict__ xh, const int* __restrict__ dst,
        int* __restrict__ matrix, int* __restrict__ ovfCnt) {
    __shared__ int hist[NB];
    int blk = blockIdx.x, tid = threadIdx.x;
    int i = blk * 256 + tid;                 // exactly 1.6M threads
    if (i == 0) ovfCnt[0] = 0;
    float4 v = x4[i];
    ushort4 o;
    o.x = __half_as_ushort(__float2half(v.x));
    o.y = __half_as_ushort(__float2half(v.y));
    o.z = __half_as_ushort(__float2half(v.z));
    o.w = __half_as_ushort(__float2half(v.w));
    ((ushort4*)xh)[i] = o;
    if (blk < 256) {
        for (int j = tid; j < NB; j += 256) hist[j] = 0;
        __syncthreads();
        int base = blk * EPB;
        for (int j = tid; j < EPB; j += 256)
            atomicAdd(&hist[dst[base + j] >> 8], 1);
        __syncthreads();
        for (int j = tid; j < NB; j += 256) matrix[blk * NB + j] = hist[j];
    }
}

// P1b: per-bucket exclusive scan over 256 block counts (in-place) + totals.
__global__ void __launch_bounds__(256) p1b_scan(int* __restrict__ matrix,
                                                int* __restrict__ bucketCnt) {
    __shared__ int s[256];
    int b = blockIdx.x, t = threadIdx.x;
    int v = matrix[t * NB + b];
    s[t] = v;
    __syncthreads();
    for (int off = 1; off < 256; off <<= 1) {
        int u = (t >= off) ? s[t - off] : 0;
        __syncthreads();
        s[t] += u;
        __syncthreads();
    }
    matrix[t * NB + b] = s[t] - v;           // exclusive prefix
    if (t == 255) bucketCnt[b] = s[255];
}

// P1c: scatter packed (dlow<<17 | src) into bucket regions (stride SSTR).
// Overflow beyond BCAP: append (d, s) to ovfList (cap = E -> always fits);
// k2 replays the list. Fully correct for any degree distribution.
__global__ void __launch_bounds__(256) p1c_scatter(const int* __restrict__ src,
        const int* __restrict__ dst, const int* __restrict__ matrix,
        int* __restrict__ bucketArr, int* __restrict__ ovfCnt,
        int2* __restrict__ ovfList) {
    __shared__ int cur[NB];
    int tid = threadIdx.x, blk = blockIdx.x;
    for (int i = tid; i < NB; i += 256) cur[i] = matrix[blk * NB + i];
    __syncthreads();
    int base = blk * EPB;
    for (int i = tid; i < EPB; i += 256) {
        int e = base + i;
        int s = src[e], d = dst[e];
        int b = d >> 8;
        int pos = atomicAdd(&cur[b], 1);
        if (pos < BCAP) {
            bucketArr[(size_t)b * SSTR + pos] = ((d & 255) << 17) | s;
        } else {
            int idx = atomicAdd(ovfCnt, 1);
            ovfList[idx] = make_int2(d, s);
        }
    }
}

// P2: per-bucket fine counting sort IN-PLACE (stage bucket into LDS, scatter
// src ids back to the same global region at sorted+padded positions).
__global__ void __launch_bounds__(256) p2_build(int* __restrict__ bucketArr,
        const int* __restrict__ bucketCnt, int* __restrict__ rowptr,
        int* __restrict__ deg) {
    __shared__ int ebuf[BCAP];               // 19.5 KB
    __shared__ int hist[256], sc[256], cur[256];
    int b = blockIdx.x, t = threadIdx.x;
    int cnt = bucketCnt[b];
    if (cnt > BCAP) cnt = BCAP;
    int* arr = bucketArr + (size_t)b * SSTR;
    hist[t] = 0;
    __syncthreads();
    for (int i = t; i < cnt; i += 256) {
        int e = arr[i];
        ebuf[i] = e;
        atomicAdd(&hist[(e >> 17) & 255], 1);
    }
    __syncthreads();
    int h = hist[t];
    int pc = (h + 3) & ~3;                   // pad row to 4 ints
    sc[t] = pc;
    __syncthreads();
    for (int off = 1; off < 256; off <<= 1) {
        int u = (t >= off) ? sc[t - off] : 0;
        __syncthreads();
        sc[t] += u;
        __syncthreads();
    }
    int rbase = sc[t] - pc;                  // exclusive padded prefix
    cur[t] = rbase;
    int n = (b << 8) + t;
    if (n < N_NODES) {
        rowptr[n] = b * SSTR + rbase;
        deg[n] = h;
    }
    __syncthreads();
    for (int i = t; i < cnt; i += 256) {
        int e = ebuf[i];
        int dl = (e >> 17) & 255;
        int pos = atomicAdd(&cur[dl], 1);
        arr[pos] = e & 0x1FFFF;
    }
}

// K2 (R11 proven form): thread per (node, 4-feat chunk); 16 threads/node;
// dense in-place CSR; fp16 rows; 16 gathers in flight. Output h now fp16.
// Overflow: replay ovfList in f32 (dead path for uniform data).
__device__ __forceinline__ void addrow(float4& acc, const __half* __restrict__ xh,
                                       int s, int fq) {
    float2 raw = *(const float2*)(xh + (size_t)s * 64 + fq * 4);
    __half2 a = *(__half2*)&raw.x;
    __half2 b = *(__half2*)&raw.y;
    float2 fa = __half22float2(a);
    float2 fb = __half22float2(b);
    acc.x += fa.x; acc.y += fa.y; acc.z += fb.x; acc.w += fb.y;
}

__global__ void __launch_bounds__(256) k2_agg(const __half* __restrict__ xh,
                       __half* __restrict__ h0h, const int* __restrict__ deg,
                       const int* __restrict__ rowptr, const int* __restrict__ csr,
                       const int* __restrict__ ovfCnt,
                       const int2* __restrict__ ovfList,
                       const float* __restrict__ x) {
    int gid = blockIdx.x * 256 + threadIdx.x;   // 1.6M = N*16
    int n = gid >> 4, fq = gid & 15;
    int dc = deg[n];
    const int4* srow = (const int4*)(csr + rowptr[n]);
    // self term = 2 * fp16(x[n])
    float2 raw = *(const float2*)(xh + (size_t)n * 64 + fq * 4);
    __half2 sa = *(__half2*)&raw.x;
    __half2 sb = *(__half2*)&raw.y;
    float2 fa = __half22float2(sa);
    float2 fb = __half22float2(sb);
    float4 acc = {2.f * fa.x, 2.f * fa.y, 2.f * fb.x, 2.f * fb.y};
    int oc = ovfCnt[0];
    if (oc > 0) {                            // correctness-only path
        for (int i = 0; i < oc; ++i) {
            int2 e = ovfList[i];
            if (e.x == n) {
                const float* xr = x + (size_t)e.y * 64 + fq * 4;
                acc.x += xr[0]; acc.y += xr[1]; acc.z += xr[2]; acc.w += xr[3];
            }
        }
    }
    for (int i = 0; i < dc; i += 16) {
        int4 s4 = srow[i >> 2];
        int4 s5, s6, s7;
        if (i + 4 < dc)  s5 = srow[(i >> 2) + 1];
        if (i + 8 < dc)  s6 = srow[(i >> 2) + 2];
        if (i + 12 < dc) s7 = srow[(i >> 2) + 3];
        addrow(acc, xh, s4.x, fq);
        if (i + 1 < dc)  addrow(acc, xh, s4.y, fq);
        if (i + 2 < dc)  addrow(acc, xh, s4.z, fq);
        if (i + 3 < dc)  addrow(acc, xh, s4.w, fq);
        if (i + 4 < dc)  addrow(acc, xh, s5.x, fq);
        if (i + 5 < dc)  addrow(acc, xh, s5.y, fq);
        if (i + 6 < dc)  addrow(acc, xh, s5.z, fq);
        if (i + 7 < dc)  addrow(acc, xh, s5.w, fq);
        if (i + 8 < dc)  addrow(acc, xh, s6.x, fq);
        if (i + 9 < dc)  addrow(acc, xh, s6.y, fq);
        if (i + 10 < dc) addrow(acc, xh, s6.z, fq);
        if (i + 11 < dc) addrow(acc, xh, s6.w, fq);
        if (i + 12 < dc) addrow(acc, xh, s7.x, fq);
        if (i + 13 < dc) addrow(acc, xh, s7.y, fq);
        if (i + 14 < dc) addrow(acc, xh, s7.z, fq);
        if (i + 15 < dc) addrow(acc, xh, s7.w, fq);
    }
    ushort4 st;
    st.x = __half_as_ushort(__float2half(acc.x));
    st.y = __half_as_ushort(__float2half(acc.y));
    st.z = __half_as_ushort(__float2half(acc.z));
    st.w = __half_as_ushort(__float2half(acc.w));
    ((ushort4*)h0h)[(size_t)n * 16 + fq] = st;
}

// K3: node MLP via plain fp16 MFMA (16 nodes/wave). h input fp16 -> A-frags
// are raw half8 row loads (no conversion, no split). Weights fp16 in LDS
// (16 KB). Layer1->layer2 transpose via per-wave padded f32 Tbuf.
__global__ void __launch_bounds__(256) k3_mfma(const __half* __restrict__ h,
        __half* __restrict__ hh, const float* __restrict__ w1,
        const float* __restrict__ b1, const float* __restrict__ w2,
        const float* __restrict__ b2) {
    __shared__ half8 WF1[512], WF2[512];     // 16 KB
    __shared__ float Tbuf[4 * 16 * 68];      // 17.4 KB
    int tid = threadIdx.x;
    for (int f = tid; f < 512; f += 256) {
        int lane = f & 63, st = f >> 6;      // st 0..7
        int t = st & 3, kh = st >> 2;
        int q = lane >> 4, nl = lane & 15;
        int n = t * 16 + nl;
        int K0 = kh * 32 + q * 8;
        half8 hv1, hv2;
#pragma unroll
        for (int j = 0; j < 8; ++j) {
            hv1[j] = (_Float16)w1[(K0 + j) * 64 + n];
            hv2[j] = (_Float16)w2[(K0 + j) * 64 + n];
        }
        WF1[f] = hv1;
        WF2[f] = hv2;
    }
    __syncthreads();
    int lane = tid & 63;
    int q = lane >> 4, p = lane & 15;
    int wtid0 = blockIdx.x * 4 + (tid >> 6);
    int wtid = wtid0 < 6249 ? wtid0 : 6249;
    int n0 = wtid * 16;
    float b1t[4], b2t[4];
#pragma unroll
    for (int t = 0; t < 4; ++t) {
        b1t[t] = b1[t * 16 + p];
        b2t[t] = b2[t * 16 + p];
    }
    const half8* hrow = (const half8*)(h + (size_t)(n0 + p) * 64);
    half8 A0 = hrow[q], A1 = hrow[4 + q];
    floatx4 acc[4];
#pragma unroll
    for (int t = 0; t < 4; ++t) acc[t] = (floatx4){0.f, 0.f, 0.f, 0.f};
#pragma unroll
    for (int t = 0; t < 4; ++t) {
        acc[t] = __builtin_amdgcn_mfma_f32_16x16x32_f16(A0, WF1[t * 64 + lane],
                                                        acc[t], 0, 0, 0);
        acc[t] = __builtin_amdgcn_mfma_f32_16x16x32_f16(A1, WF1[(4 + t) * 64 + lane],
                                                        acc[t], 0, 0, 0);
    }
    float* T = Tbuf + (tid >> 6) * (16 * 68);
#pragma unroll
    for (int t = 0; t < 4; ++t) {
#pragma unroll
        for (int r = 0; r < 4; ++r)
            T[(q * 4 + r) * 68 + t * 16 + p] = fmaxf(acc[t][r] + b1t[t], 0.f);
    }
    const float* Tp = T + p * 68;
    float4 u0 = *(const float4*)(Tp + q * 8);
    float4 u1 = *(const float4*)(Tp + q * 8 + 4);
    float4 u2 = *(const float4*)(Tp + 32 + q * 8);
    float4 u3 = *(const float4*)(Tp + 32 + q * 8 + 4);
    half8 g0, g1;
    g0[0] = (_Float16)u0.x; g0[1] = (_Float16)u0.y;
    g0[2] = (_Float16)u0.z; g0[3] = (_Float16)u0.w;
    g0[4] = (_Float16)u1.x; g0[5] = (_Float16)u1.y;
    g0[6] = (_Float16)u1.z; g0[7] = (_Float16)u1.w;
    g1[0] = (_Float16)u2.x; g1[1] = (_Float16)u2.y;
    g1[2] = (_Float16)u2.z; g1[3] = (_Float16)u2.w;
    g1[4] = (_Float16)u3.x; g1[5] = (_Float16)u3.y;
    g1[6] = (_Float16)u3.z; g1[7] = (_Float16)u3.w;
#pragma unroll
    for (int t = 0; t < 4; ++t) acc[t] = (floatx4){0.f, 0.f, 0.f, 0.f};
#pragma unroll
    for (int t = 0; t < 4; ++t) {
        acc[t] = __builtin_amdgcn_mfma_f32_16x16x32_f16(g0, WF2[t * 64 + lane],
                                                        acc[t], 0, 0, 0);
        acc[t] = __builtin_amdgcn_mfma_f32_16x16x32_f16(g1, WF2[(4 + t) * 64 + lane],
                                                        acc[t], 0, 0, 0);
    }
    if (wtid0 < 6250) {
#pragma unroll
        for (int t = 0; t < 4; ++t) {
#pragma unroll
            for (int r = 0; r < 4; ++r)
                hh[(size_t)(n0 + q * 4 + r) * 64 + t * 16 + p] =
                    __float2half(fmaxf(acc[t][r] + b2t[t], 0.f));
        }
    }
}

// K4: pair decoder via plain fp16 MFMA (f32 accum), 16 pairs/wave-task.
__global__ void __launch_bounds__(256) k4_pair(const __half* __restrict__ hh,
                        const int* __restrict__ qidx,
                        const float* __restrict__ dw1, const float* __restrict__ db1,
                        const float* __restrict__ dw2, const float* __restrict__ db2,
                        float* __restrict__ out, int numWaves) {
    __shared__ half8 BF[2048];   // [s(8)][t(4)][lane(64)] -> 32 KB
    int tid = threadIdx.x;
    for (int f = tid; f < 2048; f += 256) {
        int lane = f & 63, st = f >> 6;
        int t = st & 3, s = st >> 2;
        int q = lane >> 4, nl = lane & 15;
        int n = t * 16 + nl;
        int K0 = s * 32 + q * 8;
        half8 hv;
#pragma unroll
        for (int j = 0; j < 8; ++j) hv[j] = (_Float16)dw1[(K0 + j) * 64 + n];
        BF[f] = hv;
    }
    __syncthreads();
    int lane = tid & 63;
    int q = lane >> 4, nl = lane & 15;
    float db1t[4], dw2t[4];
#pragma unroll
    for (int t = 0; t < 4; ++t) {
        db1t[t] = db1[t * 16 + nl];
        dw2t[t] = dw2[t * 16 + nl];
    }
    float db2v = db2[0];
    int wid = (blockIdx.x * 256 + tid) >> 6;
    for (int task = wid; task < NPAIRS / 16; task += numWaves) {
        int p0 = task * 16;
        int i1 = qidx[p0 + nl];
        int i2 = qidx[NPAIRS + p0 + nl];
        const half8* r1 = (const half8*)(hh + (size_t)i1 * 64);
        const half8* r2 = (const half8*)(hh + (size_t)i2 * 64);
        half8 e1a = r1[q],     e1b = r1[4 + q];
        half8 e2a = r2[q],     e2b = r2[4 + q];
        half8 sA = e1a + e2a,  sB = e1b + e2b;    // v_pk_add_f16
        half8 pA = e1a * e2a,  pB = e1b * e2b;    // v_pk_mul_f16
        floatx4 acc[4];
#pragma unroll
        for (int t = 0; t < 4; ++t) acc[t] = (floatx4){0.f, 0.f, 0.f, 0.f};

#define DO_STEP(S, AV)                                                        \
        _Pragma("unroll")                                                     \
        for (int t = 0; t < 4; ++t)                                           \
            acc[t] = __builtin_amdgcn_mfma_f32_16x16x32_f16(                  \
                (AV), BF[((S) * 4 + t) * 64 + lane], acc[t], 0, 0, 0);

        DO_STEP(0, sA)   // section 0 (e1+e2), k 0..31
        DO_STEP(1, sB)   // section 0, k 32..63
        DO_STEP(2, pA)   // section 1 (e1*e2)
        DO_STEP(3, pB)
        DO_STEP(4, e1a)  // section 2 (e1)
        DO_STEP(5, e1b)
        DO_STEP(6, e2a)  // section 3 (e2)
        DO_STEP(7, e2b)
#undef DO_STEP

        float part[4] = {0.f, 0.f, 0.f, 0.f};
#pragma unroll
        for (int t = 0; t < 4; ++t) {
#pragma unroll
            for (int r = 0; r < 4; ++r)
                part[r] = fmaf(fmaxf(acc[t][r] + db1t[t], 0.f), dw2t[t], part[r]);
        }
#pragma unroll
        for (int off = 1; off < 16; off <<= 1) {
#pragma unroll
            for (int r = 0; r < 4; ++r) part[r] += __shfl_xor(part[r], off, 64);
        }
        if (nl == 0) {
#pragma unroll
            for (int r = 0; r < 4; ++r) out[p0 + q * 4 + r] = part[r] + db2v;
        }
    }
}

extern "C" void kernel_launch(void* const* d_in, const int* in_sizes, int n_in,
                              void* d_out, int out_size, void* d_ws, size_t ws_size,
                              hipStream_t stream) {
    const float* x    = (const float*)d_in[0];   // [N,64]
    const int*   eidx = (const int*)d_in[1];     // [2,E]
    const int*   qidx = (const int*)d_in[3];     // [2,P]
    const float* w1   = (const float*)d_in[4];
    const float* b1   = (const float*)d_in[5];
    const float* w2   = (const float*)d_in[6];
    const float* b2   = (const float*)d_in[7];
    const float* dw1  = (const float*)d_in[8];   // [256,64]
    const float* db1  = (const float*)d_in[9];
    const float* dw2  = (const float*)d_in[10];  // [64]
    const float* db2  = (const float*)d_in[11];  // [1]
    float* out = (float*)d_out;                  // [P]

    // ws layout (48.41 MB total, proven-safe size; 16B aligned):
    //   h0h (fp16) @ 0          : 12,800,000 B  (GIN agg, k2 out / k3 in)
    //   xh / hh    @ 12,800,000 : 12,800,000 B  (fp16 x for k2; reused as
    //                                            fp16 h for k3->k4)
    //   bucketArr  @ 25,600,000 :  8,808,448 B  (391 x 5632 x 4, in-place CSR)
    //   ovfList    @ 34,408,448 : 12,800,000 B  (int2 x E, correctness path)
    //   rowptr     @ 47,208,448 :    400,000 B
    //   deg        @ 47,608,448 :    400,000 B
    //   matrix     @ 48,008,448 :    400,384 B
    //   bucketCnt  @ 48,408,832 :      1,564 B
    //   ovfCnt     @ 48,410,396 :          4 B
    char* ws = (char*)d_ws;
    __half* h0h       = (__half*)ws;
    __half* xh        = (__half*)(ws + 12800000);
    int*    bucketArr = (int*)(ws + 25600000);
    int2*   ovfList   = (int2*)(ws + 34408448);
    int*    rowptr    = (int*)(ws + 47208448);
    int*    deg       = (int*)(ws + 47608448);
    int*    matrix    = (int*)(ws + 48008448);
    int*    bucketCnt = (int*)(ws + 48408832);
    int*    ovfCnt    = (int*)(ws + 48410396);

    const int* src = eidx;
    const int* dst = eidx + N_EDGES;

    k0_fused<<<6250, 256, 0, stream>>>((const float4*)x, xh, dst, matrix, ovfCnt);
    p1b_scan<<<NB, 256, 0, stream>>>(matrix, bucketCnt);
    p1c_scatter<<<256, 256, 0, stream>>>(src, dst, matrix, bucketArr,
                                         ovfCnt, ovfList);
    p2_build<<<NB, 256, 0, stream>>>(bucketArr, bucketCnt, rowptr, deg);
    k2_agg<<<6250, 256, 0, stream>>>(xh, h0h, deg, rowptr, bucketArr,
                                     ovfCnt, ovfList, x);
    k3_mfma<<<1563, 256, 0, stream>>>(h0h, xh, w1, b1, w2, b2);
    const int blocks4 = 625;
    k4_pair<<<blocks4, 256, 0, stream>>>(xh, qidx, dw1, db1, dw2, db2, out,
                                         blocks4 * 4);
}

// Round 14
// 214.992 us; speedup vs baseline: 1.1368x; 1.0030x over previous
//
#include <hip/hip_runtime.h>
#include <hip/hip_bf16.h>
#include <hip/hip_fp16.h>
#include <cstdint>

#define N_NODES 100000
#define N_EDGES 1600000
#define FDIM 64
#define NPAIRS 200000
#define NB 391          // dst buckets: ceil(100000/256)
#define BCAP 4864       // bucket fill capacity (avg 4092, +12 sigma)
#define SSTR 5632       // bucket region stride (>= BCAP + 256*3 row padding)
#define EPB 6250        // edges per hist/scatter block (256 blocks)

typedef __attribute__((ext_vector_type(8))) _Float16 half8;
typedef __attribute__((ext_vector_type(4))) float floatx4;

// K0 (fused hist): xh = fp16(x) for all 6250 blocks; blocks < 256 also
// LDS-histogram dst -> matrix[block][bucket].
__global__ void __launch_bounds__(256) k0_fused(const float4* __restrict__ x4,
        __half* __restrict__ xh, const int* __restrict__ dst,
        int* __restrict__ matrix, int* __restrict__ ovfCnt) {
    __shared__ int hist[NB];
    int blk = blockIdx.x, tid = threadIdx.x;
    int i = blk * 256 + tid;                 // exactly 1.6M threads
    if (i == 0) ovfCnt[0] = 0;
    float4 v = x4[i];
    ushort4 o;
    o.x = __half_as_ushort(__float2half(v.x));
    o.y = __half_as_ushort(__float2half(v.y));
    o.z = __half_as_ushort(__float2half(v.z));
    o.w = __half_as_ushort(__float2half(v.w));
    ((ushort4*)xh)[i] = o;
    if (blk < 256) {
        for (int j = tid; j < NB; j += 256) hist[j] = 0;
        __syncthreads();
        int base = blk * EPB;
        for (int j = tid; j < EPB; j += 256)
            atomicAdd(&hist[dst[base + j] >> 8], 1);
        __syncthreads();
        for (int j = tid; j < NB; j += 256) matrix[blk * NB + j] = hist[j];
    }
}

// P1b: per-bucket exclusive scan over 256 block counts (in-place) + totals.
__global__ void __launch_bounds__(256) p1b_scan(int* __restrict__ matrix,
                                                int* __restrict__ bucketCnt) {
    __shared__ int s[256];
    int b = blockIdx.x, t = threadIdx.x;
    int v = matrix[t * NB + b];
    s[t] = v;
    __syncthreads();
    for (int off = 1; off < 256; off <<= 1) {
        int u = (t >= off) ? s[t - off] : 0;
        __syncthreads();
        s[t] += u;
        __syncthreads();
    }
    matrix[t * NB + b] = s[t] - v;           // exclusive prefix
    if (t == 255) bucketCnt[b] = s[255];
}

// P1c: scatter packed (dlow<<17 | src) into bucket regions (stride SSTR).
// R14: 1024 threads/block (4x memory parallelism; slot order within a
// (block,bucket) window is irrelevant, so larger blocks are safe).
// Overflow beyond BCAP: append to ovfList (cap = E); k2 replays it.
__global__ void __launch_bounds__(1024) p1c_scatter(const int* __restrict__ src,
        const int* __restrict__ dst, const int* __restrict__ matrix,
        int* __restrict__ bucketArr, int* __restrict__ ovfCnt,
        int2* __restrict__ ovfList) {
    __shared__ int cur[NB];
    int tid = threadIdx.x, blk = blockIdx.x;
    for (int i = tid; i < NB; i += 1024) cur[i] = matrix[blk * NB + i];
    __syncthreads();
    int base = blk * EPB;
    for (int i = tid; i < EPB; i += 1024) {
        int e = base + i;
        int s = src[e], d = dst[e];
        int b = d >> 8;
        int pos = atomicAdd(&cur[b], 1);
        if (pos < BCAP) {
            bucketArr[(size_t)b * SSTR + pos] = ((d & 255) << 17) | s;
        } else {
            int idx = atomicAdd(ovfCnt, 1);
            ovfList[idx] = make_int2(d, s);
        }
    }
}

// P2: per-bucket fine counting sort IN-PLACE.
__global__ void __launch_bounds__(256) p2_build(int* __restrict__ bucketArr,
        const int* __restrict__ bucketCnt, int* __restrict__ rowptr,
        int* __restrict__ deg) {
    __shared__ int ebuf[BCAP];               // 19.5 KB
    __shared__ int hist[256], sc[256], cur[256];
    int b = blockIdx.x, t = threadIdx.x;
    int cnt = bucketCnt[b];
    if (cnt > BCAP) cnt = BCAP;
    int* arr = bucketArr + (size_t)b * SSTR;
    hist[t] = 0;
    __syncthreads();
    for (int i = t; i < cnt; i += 256) {
        int e = arr[i];
        ebuf[i] = e;
        atomicAdd(&hist[(e >> 17) & 255], 1);
    }
    __syncthreads();
    int h = hist[t];
    int pc = (h + 3) & ~3;                   // pad row to 4 ints
    sc[t] = pc;
    __syncthreads();
    for (int off = 1; off < 256; off <<= 1) {
        int u = (t >= off) ? sc[t - off] : 0;
        __syncthreads();
        sc[t] += u;
        __syncthreads();
    }
    int rbase = sc[t] - pc;                  // exclusive padded prefix
    cur[t] = rbase;
    int n = (b << 8) + t;
    if (n < N_NODES) {
        rowptr[n] = b * SSTR + rbase;
        deg[n] = h;
    }
    __syncthreads();
    for (int i = t; i < cnt; i += 256) {
        int e = ebuf[i];
        int dl = (e >> 17) & 255;
        int pos = atomicAdd(&cur[dl], 1);
        arr[pos] = e & 0x1FFFF;
    }
}

// K2 (R11 proven form): thread per (node, 4-feat chunk); fp16 rows;
// 16 gathers in flight. Output h fp16.
__device__ __forceinline__ void addrow(float4& acc, const __half* __restrict__ xh,
                                       int s, int fq) {
    float2 raw = *(const float2*)(xh + (size_t)s * 64 + fq * 4);
    __half2 a = *(__half2*)&raw.x;
    __half2 b = *(__half2*)&raw.y;
    float2 fa = __half22float2(a);
    float2 fb = __half22float2(b);
    acc.x += fa.x; acc.y += fa.y; acc.z += fb.x; acc.w += fb.y;
}

__global__ void __launch_bounds__(256) k2_agg(const __half* __restrict__ xh,
                       __half* __restrict__ h0h, const int* __restrict__ deg,
                       const int* __restrict__ rowptr, const int* __restrict__ csr,
                       const int* __restrict__ ovfCnt,
                       const int2* __restrict__ ovfList,
                       const float* __restrict__ x) {
    int gid = blockIdx.x * 256 + threadIdx.x;   // 1.6M = N*16
    int n = gid >> 4, fq = gid & 15;
    int dc = deg[n];
    const int4* srow = (const int4*)(csr + rowptr[n]);
    float2 raw = *(const float2*)(xh + (size_t)n * 64 + fq * 4);
    __half2 sa = *(__half2*)&raw.x;
    __half2 sb = *(__half2*)&raw.y;
    float2 fa = __half22float2(sa);
    float2 fb = __half22float2(sb);
    float4 acc = {2.f * fa.x, 2.f * fa.y, 2.f * fb.x, 2.f * fb.y};
    int oc = ovfCnt[0];
    if (oc > 0) {                            // correctness-only path
        for (int i = 0; i < oc; ++i) {
            int2 e = ovfList[i];
            if (e.x == n) {
                const float* xr = x + (size_t)e.y * 64 + fq * 4;
                acc.x += xr[0]; acc.y += xr[1]; acc.z += xr[2]; acc.w += xr[3];
            }
        }
    }
    for (int i = 0; i < dc; i += 16) {
        int4 s4 = srow[i >> 2];
        int4 s5, s6, s7;
        if (i + 4 < dc)  s5 = srow[(i >> 2) + 1];
        if (i + 8 < dc)  s6 = srow[(i >> 2) + 2];
        if (i + 12 < dc) s7 = srow[(i >> 2) + 3];
        addrow(acc, xh, s4.x, fq);
        if (i + 1 < dc)  addrow(acc, xh, s4.y, fq);
        if (i + 2 < dc)  addrow(acc, xh, s4.z, fq);
        if (i + 3 < dc)  addrow(acc, xh, s4.w, fq);
        if (i + 4 < dc)  addrow(acc, xh, s5.x, fq);
        if (i + 5 < dc)  addrow(acc, xh, s5.y, fq);
        if (i + 6 < dc)  addrow(acc, xh, s5.z, fq);
        if (i + 7 < dc)  addrow(acc, xh, s5.w, fq);
        if (i + 8 < dc)  addrow(acc, xh, s6.x, fq);
        if (i + 9 < dc)  addrow(acc, xh, s6.y, fq);
        if (i + 10 < dc) addrow(acc, xh, s6.z, fq);
        if (i + 11 < dc) addrow(acc, xh, s6.w, fq);
        if (i + 12 < dc) addrow(acc, xh, s7.x, fq);
        if (i + 13 < dc) addrow(acc, xh, s7.y, fq);
        if (i + 14 < dc) addrow(acc, xh, s7.z, fq);
        if (i + 15 < dc) addrow(acc, xh, s7.w, fq);
    }
    ushort4 st;
    st.x = __half_as_ushort(__float2half(acc.x));
    st.y = __half_as_ushort(__float2half(acc.y));
    st.z = __half_as_ushort(__float2half(acc.z));
    st.w = __half_as_ushort(__float2half(acc.w));
    ((ushort4*)h0h)[(size_t)n * 16 + fq] = st;
}

// K3: node MLP via plain fp16 MFMA (16 nodes/wave).
__global__ void __launch_bounds__(256) k3_mfma(const __half* __restrict__ h,
        __half* __restrict__ hh, const float* __restrict__ w1,
        const float* __restrict__ b1, const float* __restrict__ w2,
        const float* __restrict__ b2) {
    __shared__ half8 WF1[512], WF2[512];     // 16 KB
    __shared__ float Tbuf[4 * 16 * 68];      // 17.4 KB
    int tid = threadIdx.x;
    for (int f = tid; f < 512; f += 256) {
        int lane = f & 63, st = f >> 6;
        int t = st & 3, kh = st >> 2;
        int q = lane >> 4, nl = lane & 15;
        int n = t * 16 + nl;
        int K0 = kh * 32 + q * 8;
        half8 hv1, hv2;
#pragma unroll
        for (int j = 0; j < 8; ++j) {
            hv1[j] = (_Float16)w1[(K0 + j) * 64 + n];
            hv2[j] = (_Float16)w2[(K0 + j) * 64 + n];
        }
        WF1[f] = hv1;
        WF2[f] = hv2;
    }
    __syncthreads();
    int lane = tid & 63;
    int q = lane >> 4, p = lane & 15;
    int wtid0 = blockIdx.x * 4 + (tid >> 6);
    int wtid = wtid0 < 6249 ? wtid0 : 6249;
    int n0 = wtid * 16;
    float b1t[4], b2t[4];
#pragma unroll
    for (int t = 0; t < 4; ++t) {
        b1t[t] = b1[t * 16 + p];
        b2t[t] = b2[t * 16 + p];
    }
    const half8* hrow = (const half8*)(h + (size_t)(n0 + p) * 64);
    half8 A0 = hrow[q], A1 = hrow[4 + q];
    floatx4 acc[4];
#pragma unroll
    for (int t = 0; t < 4; ++t) acc[t] = (floatx4){0.f, 0.f, 0.f, 0.f};
#pragma unroll
    for (int t = 0; t < 4; ++t) {
        acc[t] = __builtin_amdgcn_mfma_f32_16x16x32_f16(A0, WF1[t * 64 + lane],
                                                        acc[t], 0, 0, 0);
        acc[t] = __builtin_amdgcn_mfma_f32_16x16x32_f16(A1, WF1[(4 + t) * 64 + lane],
                                                        acc[t], 0, 0, 0);
    }
    float* T = Tbuf + (tid >> 6) * (16 * 68);
#pragma unroll
    for (int t = 0; t < 4; ++t) {
#pragma unroll
        for (int r = 0; r < 4; ++r)
            T[(q * 4 + r) * 68 + t * 16 + p] = fmaxf(acc[t][r] + b1t[t], 0.f);
    }
    const float* Tp = T + p * 68;
    float4 u0 = *(const float4*)(Tp + q * 8);
    float4 u1 = *(const float4*)(Tp + q * 8 + 4);
    float4 u2 = *(const float4*)(Tp + 32 + q * 8);
    float4 u3 = *(const float4*)(Tp + 32 + q * 8 + 4);
    half8 g0, g1;
    g0[0] = (_Float16)u0.x; g0[1] = (_Float16)u0.y;
    g0[2] = (_Float16)u0.z; g0[3] = (_Float16)u0.w;
    g0[4] = (_Float16)u1.x; g0[5] = (_Float16)u1.y;
    g0[6] = (_Float16)u1.z; g0[7] = (_Float16)u1.w;
    g1[0] = (_Float16)u2.x; g1[1] = (_Float16)u2.y;
    g1[2] = (_Float16)u2.z; g1[3] = (_Float16)u2.w;
    g1[4] = (_Float16)u3.x; g1[5] = (_Float16)u3.y;
    g1[6] = (_Float16)u3.z; g1[7] = (_Float16)u3.w;
#pragma unroll
    for (int t = 0; t < 4; ++t) acc[t] = (floatx4){0.f, 0.f, 0.f, 0.f};
#pragma unroll
    for (int t = 0; t < 4; ++t) {
        acc[t] = __builtin_amdgcn_mfma_f32_16x16x32_f16(g0, WF2[t * 64 + lane],
                                                        acc[t], 0, 0, 0);
        acc[t] = __builtin_amdgcn_mfma_f32_16x16x32_f16(g1, WF2[(4 + t) * 64 + lane],
                                                        acc[t], 0, 0, 0);
    }
    if (wtid0 < 6250) {
#pragma unroll
        for (int t = 0; t < 4; ++t) {
#pragma unroll
            for (int r = 0; r < 4; ++r)
                hh[(size_t)(n0 + q * 4 + r) * 64 + t * 16 + p] =
                    __float2half(fmaxf(acc[t][r] + b2t[t], 0.f));
        }
    }
}

// K4: pair decoder via plain fp16 MFMA. R14: 512 threads/block (8 waves) --
// same 625 blocks (staging unchanged) but 2x waves (~20/CU) against the
// latency-bound random 128B row gathers.
__global__ void __launch_bounds__(512) k4_pair(const __half* __restrict__ hh,
                        const int* __restrict__ qidx,
                        const float* __restrict__ dw1, const float* __restrict__ db1,
                        const float* __restrict__ dw2, const float* __restrict__ db2,
                        float* __restrict__ out, int numWaves) {
    __shared__ half8 BF[2048];   // [s(8)][t(4)][lane(64)] -> 32 KB
    int tid = threadIdx.x;
    for (int f = tid; f < 2048; f += 512) {
        int lane = f & 63, st = f >> 6;
        int t = st & 3, s = st >> 2;
        int q = lane >> 4, nl = lane & 15;
        int n = t * 16 + nl;
        int K0 = s * 32 + q * 8;
        half8 hv;
#pragma unroll
        for (int j = 0; j < 8; ++j) hv[j] = (_Float16)dw1[(K0 + j) * 64 + n];
        BF[f] = hv;
    }
    __syncthreads();
    int lane = tid & 63;
    int q = lane >> 4, nl = lane & 15;
    float db1t[4], dw2t[4];
#pragma unroll
    for (int t = 0; t < 4; ++t) {
        db1t[t] = db1[t * 16 + nl];
        dw2t[t] = dw2[t * 16 + nl];
    }
    float db2v = db2[0];
    int wid = (blockIdx.x * 512 + tid) >> 6;
    for (int task = wid; task < NPAIRS / 16; task += numWaves) {
        int p0 = task * 16;
        int i1 = qidx[p0 + nl];
        int i2 = qidx[NPAIRS + p0 + nl];
        const half8* r1 = (const half8*)(hh + (size_t)i1 * 64);
        const half8* r2 = (const half8*)(hh + (size_t)i2 * 64);
        half8 e1a = r1[q],     e1b = r1[4 + q];
        half8 e2a = r2[q],     e2b = r2[4 + q];
        half8 sA = e1a + e2a,  sB = e1b + e2b;    // v_pk_add_f16
        half8 pA = e1a * e2a,  pB = e1b * e2b;    // v_pk_mul_f16
        floatx4 acc[4];
#pragma unroll
        for (int t = 0; t < 4; ++t) acc[t] = (floatx4){0.f, 0.f, 0.f, 0.f};

#define DO_STEP(S, AV)                                                        \
        _Pragma("unroll")                                                     \
        for (int t = 0; t < 4; ++t)                                           \
            acc[t] = __builtin_amdgcn_mfma_f32_16x16x32_f16(                  \
                (AV), BF[((S) * 4 + t) * 64 + lane], acc[t], 0, 0, 0);

        DO_STEP(0, sA)   // section 0 (e1+e2), k 0..31
        DO_STEP(1, sB)   // section 0, k 32..63
        DO_STEP(2, pA)   // section 1 (e1*e2)
        DO_STEP(3, pB)
        DO_STEP(4, e1a)  // section 2 (e1)
        DO_STEP(5, e1b)
        DO_STEP(6, e2a)  // section 3 (e2)
        DO_STEP(7, e2b)
#undef DO_STEP

        float part[4] = {0.f, 0.f, 0.f, 0.f};
#pragma unroll
        for (int t = 0; t < 4; ++t) {
#pragma unroll
            for (int r = 0; r < 4; ++r)
                part[r] = fmaf(fmaxf(acc[t][r] + db1t[t], 0.f), dw2t[t], part[r]);
        }
#pragma unroll
        for (int off = 1; off < 16; off <<= 1) {
#pragma unroll
            for (int r = 0; r < 4; ++r) part[r] += __shfl_xor(part[r], off, 64);
        }
        if (nl == 0) {
#pragma unroll
            for (int r = 0; r < 4; ++r) out[p0 + q * 4 + r] = part[r] + db2v;
        }
    }
}

extern "C" void kernel_launch(void* const* d_in, const int* in_sizes, int n_in,
                              void* d_out, int out_size, void* d_ws, size_t ws_size,
                              hipStream_t stream) {
    const float* x    = (const float*)d_in[0];   // [N,64]
    const int*   eidx = (const int*)d_in[1];     // [2,E]
    const int*   qidx = (const int*)d_in[3];     // [2,P]
    const float* w1   = (const float*)d_in[4];
    const float* b1   = (const float*)d_in[5];
    const float* w2   = (const float*)d_in[6];
    const float* b2   = (const float*)d_in[7];
    const float* dw1  = (const float*)d_in[8];   // [256,64]
    const float* db1  = (const float*)d_in[9];
    const float* dw2  = (const float*)d_in[10];  // [64]
    const float* db2  = (const float*)d_in[11];  // [1]
    float* out = (float*)d_out;                  // [P]

    // ws layout (48.41 MB total; 16B aligned):
    //   h0h (fp16) @ 0          : 12,800,000 B
    //   xh / hh    @ 12,800,000 : 12,800,000 B
    //   bucketArr  @ 25,600,000 :  8,808,448 B
    //   ovfList    @ 34,408,448 : 12,800,000 B
    //   rowptr     @ 47,208,448 :    400,000 B
    //   deg        @ 47,608,448 :    400,000 B
    //   matrix     @ 48,008,448 :    400,384 B
    //   bucketCnt  @ 48,408,832 :      1,564 B
    //   ovfCnt     @ 48,410,396 :          4 B
    char* ws = (char*)d_ws;
    __half* h0h       = (__half*)ws;
    __half* xh        = (__half*)(ws + 12800000);
    int*    bucketArr = (int*)(ws + 25600000);
    int2*   ovfList   = (int2*)(ws + 34408448);
    int*    rowptr    = (int*)(ws + 47208448);
    int*    deg       = (int*)(ws + 47608448);
    int*    matrix    = (int*)(ws + 48008448);
    int*    bucketCnt = (int*)(ws + 48408832);
    int*    ovfCnt    = (int*)(ws + 48410396);

    const int* src = eidx;
    const int* dst = eidx + N_EDGES;

    k0_fused<<<6250, 256, 0, stream>>>((const float4*)x, xh, dst, matrix, ovfCnt);
    p1b_scan<<<NB, 256, 0, stream>>>(matrix, bucketCnt);
    p1c_scatter<<<256, 1024, 0, stream>>>(src, dst, matrix, bucketArr,
                                          ovfCnt, ovfList);
    p2_build<<<NB, 256, 0, stream>>>(bucketArr, bucketCnt, rowptr, deg);
    k2_agg<<<6250, 256, 0, stream>>>(xh, h0h, deg, rowptr, bucketArr,
                                     ovfCnt, ovfList, x);
    k3_mfma<<<1563, 256, 0, stream>>>(h0h, xh, w1, b1, w2, b2);
    // K4: 625 blocks x 8 waves = 5000 waves (2.5 tasks/wave)
    const int blocks4 = 625;
    k4_pair<<<blocks4, 512, 0, stream>>>(xh, qidx, dw1, db1, dw2, db2, out,
                                         blocks4 * 8);
}